// Round 19
// baseline (133.560 us; speedup 1.0000x reference)
//
#include <hip/hip_runtime.h>
#include <math.h>

#define II 2048
#define BB 256
#define JJ 10
#define ICH 16            // i's per block
#define ICHUNKS (II/ICH)  // 128
#define SJE (BB*JJ*16)    // 40960
#define CPAD 20           // c_tile row stride (halves): banks spread, 8B-aligned

typedef __attribute__((address_space(3))) unsigned lds_u32;
typedef __attribute__((address_space(1))) const unsigned glb_u32;
typedef _Float16 h4 __attribute__((ext_vector_type(4)));
typedef _Float16 h8 __attribute__((ext_vector_type(8)));
typedef __attribute__((ext_vector_type(4))) float f32x4;

__device__ __forceinline__ void gload16(const void* g, void* l) {
  __builtin_amdgcn_global_load_lds((glb_u32*)g, (lds_u32*)l, 16, 0, 0);
}

// DPP row (16-lane) rotate: VALU-pipe cross-lane, no LDS traffic.
template<int N>
__device__ __forceinline__ float rrot16(float v) {
  const int i = __float_as_int(v);
  return __int_as_float(__builtin_amdgcn_update_dpp(i, i, 0x120 + N, 0xF, 0xF, false));
}
__device__ __forceinline__ float rsum16(float v) {
  v += rrot16<8>(v); v += rrot16<4>(v); v += rrot16<2>(v); v += rrot16<1>(v);
  return v;
}
__device__ __forceinline__ float xor16swz(float v) {  // lane ^ 16 (within 32-halves)
  return __int_as_float(__builtin_amdgcn_ds_swizzle(__float_as_int(v), 0x401F));
}

// -------- prep: fp32 -> f16 copies of x and W in ws --------
#define XF4 (BB * II * 8 / 4)        // 1048576 float4 slots
#define WF4 (JJ * II * 128 / 4)      // 655360
__global__ __launch_bounds__(256)
void prep_half(const float* __restrict__ x, const float* __restrict__ W,
               _Float16* __restrict__ xh, _Float16* __restrict__ wh) {
  for (int s = blockIdx.x * 256 + threadIdx.x; s < XF4 + WF4; s += gridDim.x * 256) {
    const float4 v = (s < XF4) ? *reinterpret_cast<const float4*>(x + (size_t)s * 4)
                               : *reinterpret_cast<const float4*>(W + (size_t)(s - XF4) * 4);
    h4 o; o.x = (_Float16)v.x; o.y = (_Float16)v.y; o.z = (_Float16)v.z; o.w = (_Float16)v.w;
    _Float16* dst = (s < XF4) ? (xh + (size_t)s * 4) : (wh + (size_t)(s - XF4) * 4);
    *reinterpret_cast<h4*>(dst) = o;
  }
}

// -------- PASS0 as f16 MFMA GEMM (s0 = x.W^T over (i,d); c==0.1 deferred) --------
__global__ __launch_bounds__(256)
void pass0_mfma(const _Float16* __restrict__ xh, const _Float16* __restrict__ wh,
                float* __restrict__ part) {
  const int t = threadIdx.x, wid = t >> 6, lane = t & 63;
  const int lg = lane >> 4, lm = lane & 15;
  const int chunk = blockIdx.x * 4 + wid;      // 0..127
  const int mb = blockIdx.y * 16;
  f32x4 acc0 = {0,0,0,0}, acc1 = {0,0,0,0}, acc2 = {0,0,0,0}, acc3 = {0,0,0,0};
  f32x4 acc4_ = {0,0,0,0}, acc5 = {0,0,0,0}, acc6 = {0,0,0,0}, acc7 = {0,0,0,0};
  f32x4 acc8 = {0,0,0,0}, acc9 = {0,0,0,0};
  const int ibase = chunk * 16;
#pragma unroll
  for (int ks = 0; ks < 4; ++ks) {
    const int i = ibase + ks * 4 + lg;
    const h8 a = *reinterpret_cast<const h8*>(xh + ((size_t)(mb + lm) * II + i) * 8);
#define MM(J, ACC)                                                              \
    {                                                                           \
      const h8 bv = *reinterpret_cast<const h8*>(                               \
          wh + (((size_t)(J) * II + i) * 16 + lm) * 8);                         \
      ACC = __builtin_amdgcn_mfma_f32_16x16x32_f16(a, bv, ACC, 0, 0, 0);        \
    }
    MM(0, acc0) MM(1, acc1) MM(2, acc2) MM(3, acc3) MM(4, acc4_)
    MM(5, acc5) MM(6, acc6) MM(7, acc7) MM(8, acc8) MM(9, acc9)
#undef MM
  }
  float* base = part + (size_t)chunk * SJE;
#define ST(J, ACC)                                                        \
  {                                                                       \
    _Pragma("unroll")                                                     \
    for (int r = 0; r < 4; ++r)                                           \
      base[((size_t)(mb + lg * 4 + r) * JJ + (J)) * 16 + lm] = ACC[r];    \
  }
  ST(0, acc0) ST(1, acc1) ST(2, acc2) ST(3, acc3) ST(4, acc4_)
  ST(5, acc5) ST(6, acc6) ST(7, acc7) ST(8, acc8) ST(9, acc9)
#undef ST
}

// -------- PASS1/2: swapped-operand MFMA routing, i-pair software pipeline --------
// MSTEP(i): 10 MFMA (rolling W reload -> i+1) + lane-local logit partial (f32)
//           + pack uh -> h4.   SSTEP(i): cross-lane e-reduce, exp, tree-D, rcp,
//           acc fma (from h4), c_tile.  Schedule: MSTEP(i+1) ; SSTEP(i) with
//           A/B buffers -> MFMA issue + load latency hide under softmax VALU.
template<int PASS>
__global__ __launch_bounds__(128, 1)
void routing_mfma(const _Float16* __restrict__ xh, const _Float16* __restrict__ wh,
                  const float* __restrict__ o_eff, float* __restrict__ part,
                  float* __restrict__ out) {
  __shared__ __align__(16) float s_acc[16 * 164];                   // 10.25 KB
  __shared__ _Float16 c_tile[(PASS == 2) ? (16 * JJ * CPAD) : 4];   // 6.25 KB (PASS2)

  const int t = threadIdx.x;
  const int w = t >> 6;                // wave 0/1
  const int lane = t & 63;
  const int lm = lane & 15;            // b-sub (MFMA col)
  const int eg = lane >> 4;            // e-group (MFMA row quad)
  const int ic = blockIdx.x;           // i-chunk (XCD = ic % 8)
  const int b0 = blockIdx.y * 16;
  const int b = b0 + lm;
  const int i0 = ic * ICH;

  // o[b, j, eg-slice], i-invariant
  float4 o[JJ];
#pragma unroll
  for (int j = 0; j < JJ; ++j)
    o[j] = *reinterpret_cast<const float4*>(
        o_eff + ((size_t)b * JJ + j) * 16 + eg * 4);

  f32x4 acc[JJ];
#pragma unroll
  for (int j = 0; j < JJ; ++j) acc[j] = f32x4{0.f, 0.f, 0.f, 0.f};

  const f32x4 z4 = {0.f, 0.f, 0.f, 0.f};
  h8 xfrag = {0, 0, 0, 0, 0, 0, 0, 0};   // lanes>=16 stay zero forever
  h8 wf[JJ];
#pragma unroll
  for (int j = 0; j < JJ; ++j) wf[j] = h8{0, 0, 0, 0, 0, 0, 0, 0};

  const _Float16* xrow = xh + (size_t)b * II * 8;
  const int ibeg = i0 + w * 8;

  // prologue: load the first i's full batch
  if (lane < 16) {
    xfrag = *reinterpret_cast<const h8*>(xrow + (size_t)ibeg * 8);
#pragma unroll
    for (int j = 0; j < JJ; ++j)
      wf[j] = *reinterpret_cast<const h8*>(
          wh + (((size_t)j * II + ibeg) * 16 + lm) * 8);
  }

  float lgA[JJ], lgB[JJ];
  h4 upA[JJ], upB[JJ];

#define MSTEP(LG, UP, INEXT)                                                  \
  {                                                                           \
    const int inx_ = (INEXT);                                                 \
    _Pragma("unroll")                                                         \
    for (int j = 0; j < JJ; ++j) {                                            \
      const f32x4 uh_ =                                                       \
          __builtin_amdgcn_mfma_f32_16x16x32_f16(wf[j], xfrag, z4, 0, 0, 0);  \
      if (lane < 16)          /* rolling reload: frag j -> next i */          \
        wf[j] = *reinterpret_cast<const h8*>(                                 \
            wh + (((size_t)j * II + inx_) * 16 + lm) * 8);                    \
      float v_ = o[j].x * uh_[0];                                             \
      v_ = fmaf(o[j].y, uh_[1], v_);                                          \
      v_ = fmaf(o[j].z, uh_[2], v_);                                          \
      v_ = fmaf(o[j].w, uh_[3], v_);                                          \
      LG[j] = v_;                                                             \
      h4 u_;                                                                  \
      u_.x = (_Float16)uh_[0]; u_.y = (_Float16)uh_[1];                       \
      u_.z = (_Float16)uh_[2]; u_.w = (_Float16)uh_[3];                       \
      UP[j] = u_;                                                             \
    }                                                                         \
    if (lane < 16)            /* x consumed by all 10 MFMAs; reload last */   \
      xfrag = *reinterpret_cast<const h8*>(xrow + (size_t)inx_ * 8);          \
  }

#define SSTEP(LG, UP, IL)                                                     \
  {                                                                           \
    float p_[JJ];                                                             \
    _Pragma("unroll")                                                         \
    for (int j = 0; j < JJ; ++j) {                                            \
      float v_ = LG[j];                                                       \
      v_ += xor16swz(v_);                                                     \
      v_ += __shfl_xor(v_, 32);                                               \
      p_[j] = __expf(v_);    /* no max-sub: logits bounded, fp32 safe */      \
    }                                                                         \
    const float d01_ = p_[0] + p_[1], d23_ = p_[2] + p_[3];                   \
    const float d45_ = p_[4] + p_[5], d67_ = p_[6] + p_[7];                   \
    const float d89_ = p_[8] + p_[9];                                         \
    const float D_ = (d01_ + d23_) + (d45_ + d67_) + d89_;                    \
    const float rD_ = __builtin_amdgcn_rcpf(D_);                              \
    _Pragma("unroll")                                                         \
    for (int j = 0; j < JJ; ++j) {                                            \
      const float c_ = p_[j] * rD_;                                           \
      acc[j][0] = fmaf(c_, (float)UP[j].x, acc[j][0]);                        \
      acc[j][1] = fmaf(c_, (float)UP[j].y, acc[j][1]);                        \
      acc[j][2] = fmaf(c_, (float)UP[j].z, acc[j][2]);                        \
      acc[j][3] = fmaf(c_, (float)UP[j].w, acc[j][3]);                        \
      if (PASS == 2) {                                                        \
        const int owner_ = (j >= 9) ? 3 : (j / 3);                            \
        if (eg == owner_)                                                     \
          c_tile[(lm * JJ + j) * CPAD + (IL)] = (_Float16)c_;                 \
      }                                                                       \
    }                                                                         \
  }

  MSTEP(lgA, upA, ibeg + 1)
#pragma unroll 1
  for (int k = 0; k < 3; ++k) {
    MSTEP(lgB, upB, ibeg + 2 * k + 2)
    SSTEP(lgA, upA, w * 8 + 2 * k)
    MSTEP(lgA, upA, ibeg + 2 * k + 3)
    SSTEP(lgB, upB, w * 8 + 2 * k + 1)
  }
  MSTEP(lgB, upB, ibeg + 7)      // consumes i7 frags; redundant reload (clamp)
  SSTEP(lgA, upA, w * 8 + 6)
  SSTEP(lgB, upB, w * 8 + 7)
#undef MSTEP
#undef SSTEP

  // combine the two waves' acc and store part
  if (w == 0) {
#pragma unroll
    for (int j = 0; j < JJ; ++j)
      *reinterpret_cast<f32x4*>(&s_acc[lm * 164 + j * 16 + eg * 4]) = acc[j];
  }
  __syncthreads();
  if (w == 1) {
#pragma unroll
    for (int j = 0; j < JJ; ++j) {
      f32x4 v = *reinterpret_cast<const f32x4*>(&s_acc[lm * 164 + j * 16 + eg * 4]);
      v += acc[j];
      *reinterpret_cast<f32x4*>(
          part + (size_t)ic * SJE + ((size_t)b * JJ + j) * 16 + eg * 4) = v;
    }
  }

  if (PASS == 2) {
    // coalesced c out: 160 rows x 16 i-floats
    for (int s = t; s < 16 * JJ * (ICH / 4); s += 128) {
      const int row = s >> 2, q = s & 3;
      const int bb = row / JJ, jj = row - bb * JJ;
      const h4 cv = *reinterpret_cast<const h4*>(&c_tile[row * CPAD + q * 4]);
      float4 ov;
      ov.x = (float)cv.x; ov.y = (float)cv.y; ov.z = (float)cv.z; ov.w = (float)cv.w;
      *reinterpret_cast<float4*>(
          out + ((size_t)(b0 + bb) * JJ + jj) * 2064 + 16 + i0 + q * 4) = ov;
    }
  }
}

// fused: reduce over 128 i-chunk partials + squash + output/o_eff update
__global__ __launch_bounds__(256)
void finish_pass(const float* __restrict__ part, float* __restrict__ o_eff,
                 float* __restrict__ out, int pass) {
  const int idx = blockIdx.x * 256 + threadIdx.x;
  float a = 0.f;
#pragma unroll 8
  for (int k = 0; k < ICHUNKS; ++k) a += part[(size_t)k * SJE + idx];
  if (pass == 0) a *= 0.1f;
  const float s2 = rsum16(a * a);
  const float scale = s2 / ((1.f + s2) * sqrtf(s2 + 1e-7f));
  const float v = scale * a;
  if (pass == 0) o_eff[idx] = v;
  else if (pass == 1) o_eff[idx] += v;
  else out[(size_t)(idx >> 4) * 2064 + (idx & 15)] = v;
}

// -------- fp32 atomic fallback (round-13-proven), used only if ws too small --------
#define BBLK 32
#define NBW 8
template<int PASS>
__global__ __launch_bounds__(256, 1)
void routing_pass_atomic(const float* __restrict__ x, const float* __restrict__ W,
                         const float* __restrict__ o_eff, float* __restrict__ sdst,
                         float* __restrict__ out) {
  __shared__ __align__(16) float x_lds[BBLK * ICH * 8];
  __shared__ _Float16 c_tile[(PASS == 2) ? (BBLK * JJ * 18) : 4];

  const int t = threadIdx.x;
  const int wid = t >> 6;
  const int lane = t & 63;
  const int eg = lane >> 4;
  const int j = lane & 15;
  const int jv = (j < JJ);
  const int jr = jv ? j : 0;
  const int ic = blockIdx.x;
  const int b0 = blockIdx.y * BBLK;
  const int bw = __builtin_amdgcn_readfirstlane(b0 + wid * NBW);
  const int i0 = ic * ICH;
  const float* wbase = W + ((size_t)jr * II + i0) * 128 + eg * 32;

  float4 o4[NBW];
  if (PASS > 0) {
#pragma unroll
    for (int nb = 0; nb < NBW; ++nb)
      o4[nb] = *reinterpret_cast<const float4*>(
          o_eff + ((size_t)(bw + nb) * JJ + jr) * 16 + eg * 4);
  }
  float4 acc4[NBW];
#pragma unroll
  for (int nb = 0; nb < NBW; ++nb) acc4[nb] = make_float4(0.f, 0.f, 0.f, 0.f);

#pragma unroll
  for (int k = 0; k < 4; ++k) {
    const int s = k * 256 + t;
    const int bl = s >> 5, rem = s & 31, il = rem >> 1, h = rem & 1;
    gload16(x + ((size_t)(b0 + bl) * II + i0 + il) * 8 + h * 4,
            &x_lds[(k * 256 + wid * 64) * 4]);
  }
  __syncthreads();

#pragma unroll 1
  for (int il = 0; il < ICH; ++il) {
    const float* wp = wbase + il * 128;
    float4 wv[8];
#pragma unroll
    for (int r = 0; r < 8; ++r)
      wv[r] = *reinterpret_cast<const float4*>(wp + r * 4);
#pragma unroll
    for (int nb = 0; nb < NBW; ++nb) {
      const float* xp = &x_lds[((wid * NBW + nb) * ICH + il) * 8];
      const float4 xa = *reinterpret_cast<const float4*>(xp);
      const float4 xb = *reinterpret_cast<const float4*>(xp + 4);
#define DOT8F(q, dst)                                  \
      float dst = wv[2*(q)].x * xa.x;                  \
      dst = fmaf(wv[2*(q)].y, xa.y, dst);              \
      dst = fmaf(wv[2*(q)].z, xa.z, dst);              \
      dst = fmaf(wv[2*(q)].w, xa.w, dst);              \
      dst = fmaf(wv[2*(q)+1].x, xb.x, dst);            \
      dst = fmaf(wv[2*(q)+1].y, xb.y, dst);            \
      dst = fmaf(wv[2*(q)+1].z, xb.z, dst);            \
      dst = fmaf(wv[2*(q)+1].w, xb.w, dst);
      DOT8F(0, u0) DOT8F(1, u1) DOT8F(2, u2) DOT8F(3, u3)
#undef DOT8F
      float c;
      if (PASS == 0) {
        c = 0.1f;
      } else {
        float lp = o4[nb].x * u0;
        lp = fmaf(o4[nb].y, u1, lp);
        lp = fmaf(o4[nb].z, u2, lp);
        lp = fmaf(o4[nb].w, u3, lp);
        lp += xor16swz(lp);
        lp += __shfl_xor(lp, 32);
        const float pp = jv ? __expf(lp) : 0.f;
        const float su = rsum16(pp);
        c = pp * __builtin_amdgcn_rcpf(su);
      }
      acc4[nb].x = fmaf(c, u0, acc4[nb].x);
      acc4[nb].y = fmaf(c, u1, acc4[nb].y);
      acc4[nb].z = fmaf(c, u2, acc4[nb].z);
      acc4[nb].w = fmaf(c, u3, acc4[nb].w);
      if (PASS == 2) {
        if (eg == 0 && jv)
          c_tile[((wid * NBW + nb) * JJ + j) * 18 + il] = (_Float16)c;
      }
    }
  }

  if (PASS == 2) {
    __syncthreads();
    for (int s = t; s < BBLK * JJ * ICH; s += 256) {
      const int row = s >> 4, col = s & 15;
      const int bb = row / 10, jj = row - bb * 10;
      out[((size_t)(b0 + bb) * JJ + jj) * 2064 + 16 + i0 + col] =
          (float)c_tile[row * 18 + col];
    }
  }

  if (jv) {
#pragma unroll
    for (int nb = 0; nb < NBW; ++nb) {
      float* sp = sdst + ((size_t)(bw + nb) * JJ + j) * 16 + eg * 4;
      atomicAdd(&sp[0], acc4[nb].x);
      atomicAdd(&sp[1], acc4[nb].y);
      atomicAdd(&sp[2], acc4[nb].z);
      atomicAdd(&sp[3], acc4[nb].w);
    }
  }
}

__global__ __launch_bounds__(256)
void squash_update(const float* __restrict__ s, float* __restrict__ o_eff,
                   float* __restrict__ out, int pass) {
  const int idx = blockIdx.x * blockDim.x + threadIdx.x;
  if (idx >= BB * JJ) return;
  const float* sp = s + (size_t)idx * 16;
  const float pre = (pass == 0) ? 0.1f : 1.f;
  float v[16];
  float s2 = 0.f;
#pragma unroll
  for (int e = 0; e < 16; ++e) { v[e] = pre * sp[e]; s2 = fmaf(v[e], v[e], s2); }
  const float scale = s2 / ((1.f + s2) * sqrtf(s2 + 1e-7f));
  if (pass == 0) {
    float* op = o_eff + (size_t)idx * 16;
#pragma unroll
    for (int e = 0; e < 16; ++e) op[e] = scale * v[e];
  } else if (pass == 1) {
    float* op = o_eff + (size_t)idx * 16;
#pragma unroll
    for (int e = 0; e < 16; ++e) op[e] += scale * v[e];
  } else {
    float* dst = out + (size_t)idx * 2064;
#pragma unroll
    for (int e = 0; e < 16; ++e) dst[e] = scale * v[e];
  }
}

extern "C" void kernel_launch(void* const* d_in, const int* in_sizes, int n_in,
                              void* d_out, int out_size, void* d_ws, size_t ws_size,
                              hipStream_t stream) {
  const float* x = (const float*)d_in[0];   // [256,2048,8]
  const float* W = (const float*)d_in[1];   // [10,2048,16,8]
  float* out = (float*)d_out;               // [256,10,2064]
  float* ws = (float*)d_ws;

  // ws: part | oe | xh | wh
  const size_t part_f = (size_t)ICHUNKS * SJE;              // 5242880 floats
  const size_t xh_f   = (size_t)BB * II * 8 / 2;            // 2097152 float-equivalents
  const size_t wh_f   = (size_t)JJ * II * 128 / 2;          // 1310720
  const size_t need = (part_f + SJE + xh_f + wh_f) * sizeof(float); // ~34.8 MB

  if (ws_size >= need) {
    float* part = ws;
    float* oe   = ws + part_f;
    _Float16* xh = (_Float16*)(ws + part_f + SJE);
    _Float16* wh = (_Float16*)(ws + part_f + SJE + xh_f);
    prep_half<<<2048, 256, 0, stream>>>(x, W, xh, wh);
    pass0_mfma<<<dim3(32, 16), 256, 0, stream>>>(xh, wh, part);
    finish_pass<<<SJE / 256, 256, 0, stream>>>(part, oe, out, 0);
    routing_mfma<1><<<dim3(ICHUNKS, 16), 128, 0, stream>>>(xh, wh, oe, part, nullptr);
    finish_pass<<<SJE / 256, 256, 0, stream>>>(part, oe, out, 1);
    routing_mfma<2><<<dim3(ICHUNKS, 16), 128, 0, stream>>>(xh, wh, oe, part, out);
    finish_pass<<<SJE / 256, 256, 0, stream>>>(part, oe, out, 2);
  } else {
    float* s0 = ws;
    float* s1 = ws + SJE;
    float* s2 = ws + 2 * SJE;
    float* oe = ws + 3 * SJE;
    hipMemsetAsync(ws, 0, (size_t)4 * SJE * sizeof(float), stream);
    routing_pass_atomic<0><<<dim3(ICHUNKS, BB / BBLK), 256, 0, stream>>>(x, W, nullptr, s0, nullptr);
    squash_update<<<10, 256, 0, stream>>>(s0, oe, out, 0);
    routing_pass_atomic<1><<<dim3(ICHUNKS, BB / BBLK), 256, 0, stream>>>(x, W, oe, s1, nullptr);
    squash_update<<<10, 256, 0, stream>>>(s1, oe, out, 1);
    routing_pass_atomic<2><<<dim3(ICHUNKS, BB / BBLK), 256, 0, stream>>>(x, W, oe, s2, out);
    squash_update<<<10, 256, 0, stream>>>(s2, oe, out, 2);
  }
}

// Round 20
// 114.438 us; speedup vs baseline: 1.1671x; 1.1671x over previous
//
#include <hip/hip_runtime.h>
#include <math.h>

#define II 2048
#define BB 256
#define JJ 10
#define ICH 16            // i's per block
#define ICHUNKS (II/ICH)  // 128
#define SJE (BB*JJ*16)    // 40960
#define CPAD 20           // c_tile row stride (halves)

typedef __attribute__((address_space(3))) unsigned lds_u32;
typedef __attribute__((address_space(1))) const unsigned glb_u32;
typedef _Float16 h4 __attribute__((ext_vector_type(4)));
typedef _Float16 h8 __attribute__((ext_vector_type(8)));
typedef __attribute__((ext_vector_type(4))) float f32x4;

__device__ __forceinline__ void gload16(const void* g, void* l) {
  __builtin_amdgcn_global_load_lds((glb_u32*)g, (lds_u32*)l, 16, 0, 0);
}

// DPP row (16-lane) rotate: VALU-pipe cross-lane, no LDS traffic.
template<int N>
__device__ __forceinline__ float rrot16(float v) {
  const int i = __float_as_int(v);
  return __int_as_float(__builtin_amdgcn_update_dpp(i, i, 0x120 + N, 0xF, 0xF, false));
}
__device__ __forceinline__ float rsum16(float v) {
  v += rrot16<8>(v); v += rrot16<4>(v); v += rrot16<2>(v); v += rrot16<1>(v);
  return v;
}
__device__ __forceinline__ float xor16swz(float v) {  // lane ^ 16 (within 32-halves)
  return __int_as_float(__builtin_amdgcn_ds_swizzle(__float_as_int(v), 0x401F));
}

// -------- prep: fp32 -> f16 copies of x and W in ws --------
#define XF4 (BB * II * 8 / 4)        // 1048576 float4 slots
#define WF4 (JJ * II * 128 / 4)      // 655360
__global__ __launch_bounds__(256)
void prep_half(const float* __restrict__ x, const float* __restrict__ W,
               _Float16* __restrict__ xh, _Float16* __restrict__ wh) {
  for (int s = blockIdx.x * 256 + threadIdx.x; s < XF4 + WF4; s += gridDim.x * 256) {
    const float4 v = (s < XF4) ? *reinterpret_cast<const float4*>(x + (size_t)s * 4)
                               : *reinterpret_cast<const float4*>(W + (size_t)(s - XF4) * 4);
    h4 o; o.x = (_Float16)v.x; o.y = (_Float16)v.y; o.z = (_Float16)v.z; o.w = (_Float16)v.w;
    _Float16* dst = (s < XF4) ? (xh + (size_t)s * 4) : (wh + (size_t)(s - XF4) * 4);
    *reinterpret_cast<h4*>(dst) = o;
  }
}

// -------- PASS0 as f16 MFMA GEMM (s0 = x.W^T over (i,d); c==0.1 deferred) --------
__global__ __launch_bounds__(256)
void pass0_mfma(const _Float16* __restrict__ xh, const _Float16* __restrict__ wh,
                float* __restrict__ part) {
  const int t = threadIdx.x, wid = t >> 6, lane = t & 63;
  const int lg = lane >> 4, lm = lane & 15;
  const int chunk = blockIdx.x * 4 + wid;      // 0..127
  const int mb = blockIdx.y * 16;
  f32x4 acc0 = {0,0,0,0}, acc1 = {0,0,0,0}, acc2 = {0,0,0,0}, acc3 = {0,0,0,0};
  f32x4 acc4_ = {0,0,0,0}, acc5 = {0,0,0,0}, acc6 = {0,0,0,0}, acc7 = {0,0,0,0};
  f32x4 acc8 = {0,0,0,0}, acc9 = {0,0,0,0};
  const int ibase = chunk * 16;
#pragma unroll
  for (int ks = 0; ks < 4; ++ks) {
    const int i = ibase + ks * 4 + lg;
    const h8 a = *reinterpret_cast<const h8*>(xh + ((size_t)(mb + lm) * II + i) * 8);
#define MM(J, ACC)                                                              \
    {                                                                           \
      const h8 bv = *reinterpret_cast<const h8*>(                               \
          wh + (((size_t)(J) * II + i) * 16 + lm) * 8);                         \
      ACC = __builtin_amdgcn_mfma_f32_16x16x32_f16(a, bv, ACC, 0, 0, 0);        \
    }
    MM(0, acc0) MM(1, acc1) MM(2, acc2) MM(3, acc3) MM(4, acc4_)
    MM(5, acc5) MM(6, acc6) MM(7, acc7) MM(8, acc8) MM(9, acc9)
#undef MM
  }
  float* base = part + (size_t)chunk * SJE;
#define ST(J, ACC)                                                        \
  {                                                                       \
    _Pragma("unroll")                                                     \
    for (int r = 0; r < 4; ++r)                                           \
      base[((size_t)(mb + lg * 4 + r) * JJ + (J)) * 16 + lm] = ACC[r];    \
  }
  ST(0, acc0) ST(1, acc1) ST(2, acc2) ST(3, acc3) ST(4, acc4_)
  ST(5, acc5) ST(6, acc6) ST(7, acc7) ST(8, acc8) ST(9, acc9)
#undef ST
}

// -------- PASS1/2: swapped-operand MFMA routing, maskless 4x-replicated --------
// ALL 64 lanes load the same per-lm fragment (W[j,i,e=lm,:] / x[b0+lm,i,:]);
// the K=32 MFMA sums the d-dot 4x (k-groups replicated). The 1/4 is folded
// into o (LDS staging) for logits and into finish_pass (a *= 0.25) for acc.
// Inner loop: {10x (mfma j -> logit partial j -> pack h4)} ; {11 batched
// reloads for i+1} ; {softmax + acc} -- loads' L2 latency hides under softmax.
template<int PASS>
__global__ __launch_bounds__(128)
void routing_mfma(const _Float16* __restrict__ xh, const _Float16* __restrict__ wh,
                  const float* __restrict__ o_eff, float* __restrict__ part,
                  float* __restrict__ out) {
  __shared__ __align__(16) float ols[16 * 164];   // o/4 during loop; acc-combine after
  __shared__ _Float16 c_tile[(PASS == 2) ? (16 * JJ * CPAD) : 4];

  const int t = threadIdx.x;
  const int w = t >> 6;                // wave 0/1
  const int lane = t & 63;
  const int lm = lane & 15;            // b-sub (MFMA col)
  const int eg = lane >> 4;            // e-group (MFMA row quad)
  const int ic = blockIdx.x;           // i-chunk (XCD = ic % 8)
  const int b0 = blockIdx.y * 16;
  const int b = b0 + lm;
  const int i0 = ic * ICH;

  // stage o/4 -> LDS: 640 float4 slots, row stride 164 floats
  for (int s = t; s < 640; s += 128) {
    const int bb = s / 40, rem = s - bb * 40;
    const float4 v = *reinterpret_cast<const float4*>(
        o_eff + (size_t)(b0 + bb) * 160 + rem * 4);
    float4 sv;
    sv.x = 0.25f * v.x; sv.y = 0.25f * v.y; sv.z = 0.25f * v.z; sv.w = 0.25f * v.w;
    *reinterpret_cast<float4*>(&ols[bb * 164 + rem * 4]) = sv;
  }
  __syncthreads();

  f32x4 acc[JJ];
#pragma unroll
  for (int j = 0; j < JJ; ++j) acc[j] = f32x4{0.f, 0.f, 0.f, 0.f};

  const f32x4 z4 = {0.f, 0.f, 0.f, 0.f};
  const _Float16* wp = wh + lm * 8;            // per-lane W base
  const _Float16* xp = xh + (size_t)b * II * 8;
  const int ibeg = i0 + w * 8;

  h8 wf[JJ];
  h8 xf;
  // prologue: load i = ibeg (all lanes, unmasked)
#pragma unroll
  for (int j = 0; j < JJ; ++j)
    wf[j] = *reinterpret_cast<const h8*>(wp + ((size_t)j * II + ibeg) * 128);
  xf = *reinterpret_cast<const h8*>(xp + (size_t)ibeg * 8);

#pragma unroll 1
  for (int ii = 0; ii < 8; ++ii) {
    const int il = w * 8 + ii;
    const int inx = ibeg + ((ii < 7) ? ii + 1 : ii);   // clamp: redundant last load

    // MFMA + logit partial + pack (uh transient per j)
    float lg[JJ];
    h4 up[JJ];
#pragma unroll
    for (int j = 0; j < JJ; ++j) {
      const f32x4 uhj =
          __builtin_amdgcn_mfma_f32_16x16x32_f16(wf[j], xf, z4, 0, 0, 0);
      const float4 o4 = *reinterpret_cast<const float4*>(
          &ols[lm * 164 + j * 16 + eg * 4]);           // o/4 -> logits exact
      float v = o4.x * uhj[0];
      v = fmaf(o4.y, uhj[1], v);
      v = fmaf(o4.z, uhj[2], v);
      v = fmaf(o4.w, uhj[3], v);
      lg[j] = v;
      h4 u; u.x = (_Float16)uhj[0]; u.y = (_Float16)uhj[1];
      u.z = (_Float16)uhj[2]; u.w = (_Float16)uhj[3];
      up[j] = u;
    }

    // batched reloads for i+1 (no masks; WAR-free: all MFMAs above consumed wf)
#pragma unroll
    for (int j = 0; j < JJ; ++j)
      wf[j] = *reinterpret_cast<const h8*>(wp + ((size_t)j * II + inx) * 128);
    xf = *reinterpret_cast<const h8*>(xp + (size_t)inx * 8);

    // softmax (covers the reloads' latency)
    float p[JJ];
#pragma unroll
    for (int j = 0; j < JJ; ++j) {
      float v = lg[j];
      v += xor16swz(v);             // eg pairs
      v += __shfl_xor(v, 32);       // halves -> full e-sum
      p[j] = __expf(v);             // no max-sub: logits bounded, fp32 safe
    }
    const float d01 = p[0] + p[1], d23 = p[2] + p[3];
    const float d45 = p[4] + p[5], d67 = p[6] + p[7];
    const float d89 = p[8] + p[9];
    const float D = (d01 + d23) + (d45 + d67) + d89;
    const float rD = __builtin_amdgcn_rcpf(D);
#pragma unroll
    for (int j = 0; j < JJ; ++j) {
      const float c = p[j] * rD;
      acc[j][0] = fmaf(c, (float)up[j].x, acc[j][0]);   // acc holds 4x; finish *0.25
      acc[j][1] = fmaf(c, (float)up[j].y, acc[j][1]);
      acc[j][2] = fmaf(c, (float)up[j].z, acc[j][2]);
      acc[j][3] = fmaf(c, (float)up[j].w, acc[j][3]);
      if (PASS == 2) {
        const int owner = (j >= 9) ? 3 : (j / 3);
        if (eg == owner)
          c_tile[(lm * JJ + j) * CPAD + il] = (_Float16)c;
      }
    }
  }

  // combine the two waves' acc (reuse ols as the combine buffer) and store part
  __syncthreads();                  // o reads done; c_tile writes done
  if (w == 0) {
#pragma unroll
    for (int j = 0; j < JJ; ++j)
      *reinterpret_cast<f32x4*>(&ols[lm * 164 + j * 16 + eg * 4]) = acc[j];
  }
  __syncthreads();
  if (w == 1) {
#pragma unroll
    for (int j = 0; j < JJ; ++j) {
      f32x4 v = *reinterpret_cast<const f32x4*>(&ols[lm * 164 + j * 16 + eg * 4]);
      v += acc[j];
      *reinterpret_cast<f32x4*>(
          part + (size_t)ic * SJE + ((size_t)b * JJ + j) * 16 + eg * 4) = v;
    }
  }

  if (PASS == 2) {
    // coalesced c out: 160 rows x 16 i-floats
    for (int s = t; s < 16 * JJ * (ICH / 4); s += 128) {
      const int row = s >> 2, q = s & 3;
      const int bb = row / JJ, jj = row - bb * JJ;
      const h4 cv = *reinterpret_cast<const h4*>(&c_tile[row * CPAD + q * 4]);
      float4 ov;
      ov.x = (float)cv.x; ov.y = (float)cv.y; ov.z = (float)cv.z; ov.w = (float)cv.w;
      *reinterpret_cast<float4*>(
          out + ((size_t)(b0 + bb) * JJ + jj) * 2064 + 16 + i0 + q * 4) = ov;
    }
  }
}

// fused: reduce over 128 i-chunk partials + squash + output/o_eff update
// pass0: part holds true sums (c=0.1 deferred). pass1/2: part holds 4x sums
// (maskless MFMA replication) -> scale 0.25.
__global__ __launch_bounds__(256)
void finish_pass(const float* __restrict__ part, float* __restrict__ o_eff,
                 float* __restrict__ out, int pass) {
  const int idx = blockIdx.x * 256 + threadIdx.x;
  float a = 0.f;
#pragma unroll 8
  for (int k = 0; k < ICHUNKS; ++k) a += part[(size_t)k * SJE + idx];
  a *= (pass == 0) ? 0.1f : 0.25f;
  const float s2 = rsum16(a * a);
  const float scale = s2 / ((1.f + s2) * sqrtf(s2 + 1e-7f));
  const float v = scale * a;
  if (pass == 0) o_eff[idx] = v;
  else if (pass == 1) o_eff[idx] += v;
  else out[(size_t)(idx >> 4) * 2064 + (idx & 15)] = v;
}

// -------- fp32 atomic fallback (round-13-proven), used only if ws too small --------
#define BBLK 32
#define NBW 8
template<int PASS>
__global__ __launch_bounds__(256, 1)
void routing_pass_atomic(const float* __restrict__ x, const float* __restrict__ W,
                         const float* __restrict__ o_eff, float* __restrict__ sdst,
                         float* __restrict__ out) {
  __shared__ __align__(16) float x_lds[BBLK * ICH * 8];
  __shared__ _Float16 c_tile[(PASS == 2) ? (BBLK * JJ * 18) : 4];

  const int t = threadIdx.x;
  const int wid = t >> 6;
  const int lane = t & 63;
  const int eg = lane >> 4;
  const int j = lane & 15;
  const int jv = (j < JJ);
  const int jr = jv ? j : 0;
  const int ic = blockIdx.x;
  const int b0 = blockIdx.y * BBLK;
  const int bw = __builtin_amdgcn_readfirstlane(b0 + wid * NBW);
  const int i0 = ic * ICH;
  const float* wbase = W + ((size_t)jr * II + i0) * 128 + eg * 32;

  float4 o4[NBW];
  if (PASS > 0) {
#pragma unroll
    for (int nb = 0; nb < NBW; ++nb)
      o4[nb] = *reinterpret_cast<const float4*>(
          o_eff + ((size_t)(bw + nb) * JJ + jr) * 16 + eg * 4);
  }
  float4 acc4[NBW];
#pragma unroll
  for (int nb = 0; nb < NBW; ++nb) acc4[nb] = make_float4(0.f, 0.f, 0.f, 0.f);

#pragma unroll
  for (int k = 0; k < 4; ++k) {
    const int s = k * 256 + t;
    const int bl = s >> 5, rem = s & 31, il = rem >> 1, h = rem & 1;
    gload16(x + ((size_t)(b0 + bl) * II + i0 + il) * 8 + h * 4,
            &x_lds[(k * 256 + wid * 64) * 4]);
  }
  __syncthreads();

#pragma unroll 1
  for (int il = 0; il < ICH; ++il) {
    const float* wp = wbase + il * 128;
    float4 wv[8];
#pragma unroll
    for (int r = 0; r < 8; ++r)
      wv[r] = *reinterpret_cast<const float4*>(wp + r * 4);
#pragma unroll
    for (int nb = 0; nb < NBW; ++nb) {
      const float* xp = &x_lds[((wid * NBW + nb) * ICH + il) * 8];
      const float4 xa = *reinterpret_cast<const float4*>(xp);
      const float4 xb = *reinterpret_cast<const float4*>(xp + 4);
#define DOT8F(q, dst)                                  \
      float dst = wv[2*(q)].x * xa.x;                  \
      dst = fmaf(wv[2*(q)].y, xa.y, dst);              \
      dst = fmaf(wv[2*(q)].z, xa.z, dst);              \
      dst = fmaf(wv[2*(q)].w, xa.w, dst);              \
      dst = fmaf(wv[2*(q)+1].x, xb.x, dst);            \
      dst = fmaf(wv[2*(q)+1].y, xb.y, dst);            \
      dst = fmaf(wv[2*(q)+1].z, xb.z, dst);            \
      dst = fmaf(wv[2*(q)+1].w, xb.w, dst);
      DOT8F(0, u0) DOT8F(1, u1) DOT8F(2, u2) DOT8F(3, u3)
#undef DOT8F
      float c;
      if (PASS == 0) {
        c = 0.1f;
      } else {
        float lp = o4[nb].x * u0;
        lp = fmaf(o4[nb].y, u1, lp);
        lp = fmaf(o4[nb].z, u2, lp);
        lp = fmaf(o4[nb].w, u3, lp);
        lp += xor16swz(lp);
        lp += __shfl_xor(lp, 32);
        const float pp = jv ? __expf(lp) : 0.f;
        const float su = rsum16(pp);
        c = pp * __builtin_amdgcn_rcpf(su);
      }
      acc4[nb].x = fmaf(c, u0, acc4[nb].x);
      acc4[nb].y = fmaf(c, u1, acc4[nb].y);
      acc4[nb].z = fmaf(c, u2, acc4[nb].z);
      acc4[nb].w = fmaf(c, u3, acc4[nb].w);
      if (PASS == 2) {
        if (eg == 0 && jv)
          c_tile[((wid * NBW + nb) * JJ + j) * 18 + il] = (_Float16)c;
      }
    }
  }

  if (PASS == 2) {
    __syncthreads();
    for (int s = t; s < BBLK * JJ * ICH; s += 256) {
      const int row = s >> 4, col = s & 15;
      const int bb = row / 10, jj = row - bb * 10;
      out[((size_t)(b0 + bb) * JJ + jj) * 2064 + 16 + i0 + col] =
          (float)c_tile[row * 18 + col];
    }
  }

  if (jv) {
#pragma unroll
    for (int nb = 0; nb < NBW; ++nb) {
      float* sp = sdst + ((size_t)(bw + nb) * JJ + j) * 16 + eg * 4;
      atomicAdd(&sp[0], acc4[nb].x);
      atomicAdd(&sp[1], acc4[nb].y);
      atomicAdd(&sp[2], acc4[nb].z);
      atomicAdd(&sp[3], acc4[nb].w);
    }
  }
}

__global__ __launch_bounds__(256)
void squash_update(const float* __restrict__ s, float* __restrict__ o_eff,
                   float* __restrict__ out, int pass) {
  const int idx = blockIdx.x * blockDim.x + threadIdx.x;
  if (idx >= BB * JJ) return;
  const float* sp = s + (size_t)idx * 16;
  const float pre = (pass == 0) ? 0.1f : 1.f;
  float v[16];
  float s2 = 0.f;
#pragma unroll
  for (int e = 0; e < 16; ++e) { v[e] = pre * sp[e]; s2 = fmaf(v[e], v[e], s2); }
  const float scale = s2 / ((1.f + s2) * sqrtf(s2 + 1e-7f));
  if (pass == 0) {
    float* op = o_eff + (size_t)idx * 16;
#pragma unroll
    for (int e = 0; e < 16; ++e) op[e] = scale * v[e];
  } else if (pass == 1) {
    float* op = o_eff + (size_t)idx * 16;
#pragma unroll
    for (int e = 0; e < 16; ++e) op[e] += scale * v[e];
  } else {
    float* dst = out + (size_t)idx * 2064;
#pragma unroll
    for (int e = 0; e < 16; ++e) dst[e] = scale * v[e];
  }
}

extern "C" void kernel_launch(void* const* d_in, const int* in_sizes, int n_in,
                              void* d_out, int out_size, void* d_ws, size_t ws_size,
                              hipStream_t stream) {
  const float* x = (const float*)d_in[0];   // [256,2048,8]
  const float* W = (const float*)d_in[1];   // [10,2048,16,8]
  float* out = (float*)d_out;               // [256,10,2064]
  float* ws = (float*)d_ws;

  // ws: part | oe | xh | wh
  const size_t part_f = (size_t)ICHUNKS * SJE;              // 5242880 floats
  const size_t xh_f   = (size_t)BB * II * 8 / 2;            // 2097152 float-equivalents
  const size_t wh_f   = (size_t)JJ * II * 128 / 2;          // 1310720
  const size_t need = (part_f + SJE + xh_f + wh_f) * sizeof(float); // ~34.8 MB

  if (ws_size >= need) {
    float* part = ws;
    float* oe   = ws + part_f;
    _Float16* xh = (_Float16*)(ws + part_f + SJE);
    _Float16* wh = (_Float16*)(ws + part_f + SJE + xh_f);
    prep_half<<<2048, 256, 0, stream>>>(x, W, xh, wh);
    pass0_mfma<<<dim3(32, 16), 256, 0, stream>>>(xh, wh, part);
    finish_pass<<<SJE / 256, 256, 0, stream>>>(part, oe, out, 0);
    routing_mfma<1><<<dim3(ICHUNKS, 16), 128, 0, stream>>>(xh, wh, oe, part, nullptr);
    finish_pass<<<SJE / 256, 256, 0, stream>>>(part, oe, out, 1);
    routing_mfma<2><<<dim3(ICHUNKS, 16), 128, 0, stream>>>(xh, wh, oe, part, out);
    finish_pass<<<SJE / 256, 256, 0, stream>>>(part, oe, out, 2);
  } else {
    float* s0 = ws;
    float* s1 = ws + SJE;
    float* s2 = ws + 2 * SJE;
    float* oe = ws + 3 * SJE;
    hipMemsetAsync(ws, 0, (size_t)4 * SJE * sizeof(float), stream);
    routing_pass_atomic<0><<<dim3(ICHUNKS, BB / BBLK), 256, 0, stream>>>(x, W, nullptr, s0, nullptr);
    squash_update<<<10, 256, 0, stream>>>(s0, oe, out, 0);
    routing_pass_atomic<1><<<dim3(ICHUNKS, BB / BBLK), 256, 0, stream>>>(x, W, oe, s1, nullptr);
    squash_update<<<10, 256, 0, stream>>>(s1, oe, out, 1);
    routing_pass_atomic<2><<<dim3(ICHUNKS, BB / BBLK), 256, 0, stream>>>(x, W, oe, s2, out);
    squash_update<<<10, 256, 0, stream>>>(s2, oe, out, 2);
  }
}

// Round 22
// 107.218 us; speedup vs baseline: 1.2457x; 1.0673x over previous
//
#include <hip/hip_runtime.h>
#include <math.h>

#define II 2048
#define BB 256
#define JJ 10
#define ICH 16            // i's per block
#define ICHUNKS (II/ICH)  // 128
#define SJE (BB*JJ*16)    // 40960
#define CPAD 20           // c_tile row stride (halves)

typedef __attribute__((address_space(3))) unsigned lds_u32;
typedef __attribute__((address_space(1))) const unsigned glb_u32;
typedef _Float16 h2 __attribute__((ext_vector_type(2)));
typedef _Float16 h4 __attribute__((ext_vector_type(4)));
typedef _Float16 h8 __attribute__((ext_vector_type(8)));
typedef __attribute__((ext_vector_type(4))) float f32x4;

__device__ __forceinline__ void gload16(const void* g, void* l) {
  __builtin_amdgcn_global_load_lds((glb_u32*)g, (lds_u32*)l, 16, 0, 0);
}

__device__ __forceinline__ h2 pkrtz(float a, float b) {
#if __has_builtin(__builtin_amdgcn_cvt_pkrtz)
  auto r = __builtin_amdgcn_cvt_pkrtz(a, b);   // __fp16x2 -> bit-cast to h2
  h2 o;
  __builtin_memcpy(&o, &r, sizeof(o));
  return o;
#else
  h2 r; r.x = (_Float16)a; r.y = (_Float16)b; return r;
#endif
}

// DPP row (16-lane) rotate: VALU-pipe cross-lane, no LDS traffic.
template<int N>
__device__ __forceinline__ float rrot16(float v) {
  const int i = __float_as_int(v);
  return __int_as_float(__builtin_amdgcn_update_dpp(i, i, 0x120 + N, 0xF, 0xF, false));
}
__device__ __forceinline__ float rsum16(float v) {
  v += rrot16<8>(v); v += rrot16<4>(v); v += rrot16<2>(v); v += rrot16<1>(v);
  return v;
}
__device__ __forceinline__ float xor16swz(float v) {  // lane ^ 16 (within 32-halves)
  return __int_as_float(__builtin_amdgcn_ds_swizzle(__float_as_int(v), 0x401F));
}

// -------- prep: fp32 -> f16 copies of x and W in ws --------
#define XF4 (BB * II * 8 / 4)        // 1048576 float4 slots
#define WF4 (JJ * II * 128 / 4)      // 655360
__global__ __launch_bounds__(256)
void prep_half(const float* __restrict__ x, const float* __restrict__ W,
               _Float16* __restrict__ xh, _Float16* __restrict__ wh) {
  for (int s = blockIdx.x * 256 + threadIdx.x; s < XF4 + WF4; s += gridDim.x * 256) {
    const float4 v = (s < XF4) ? *reinterpret_cast<const float4*>(x + (size_t)s * 4)
                               : *reinterpret_cast<const float4*>(W + (size_t)(s - XF4) * 4);
    h4 o; o.x = (_Float16)v.x; o.y = (_Float16)v.y; o.z = (_Float16)v.z; o.w = (_Float16)v.w;
    _Float16* dst = (s < XF4) ? (xh + (size_t)s * 4) : (wh + (size_t)(s - XF4) * 4);
    *reinterpret_cast<h4*>(dst) = o;
  }
}

// -------- PASS0 as f16 MFMA GEMM (s0 = x.W^T over (i,d); c==0.1 deferred) --------
__global__ __launch_bounds__(256)
void pass0_mfma(const _Float16* __restrict__ xh, const _Float16* __restrict__ wh,
                float* __restrict__ part) {
  const int t = threadIdx.x, wid = t >> 6, lane = t & 63;
  const int lg = lane >> 4, lm = lane & 15;
  const int chunk = blockIdx.x * 4 + wid;      // 0..127
  const int mb = blockIdx.y * 16;
  f32x4 acc0 = {0,0,0,0}, acc1 = {0,0,0,0}, acc2 = {0,0,0,0}, acc3 = {0,0,0,0};
  f32x4 acc4_ = {0,0,0,0}, acc5 = {0,0,0,0}, acc6 = {0,0,0,0}, acc7 = {0,0,0,0};
  f32x4 acc8 = {0,0,0,0}, acc9 = {0,0,0,0};
  const int ibase = chunk * 16;
#pragma unroll
  for (int ks = 0; ks < 4; ++ks) {
    const int i = ibase + ks * 4 + lg;
    const h8 a = *reinterpret_cast<const h8*>(xh + ((size_t)(mb + lm) * II + i) * 8);
#define MM(J, ACC)                                                              \
    {                                                                           \
      const h8 bv = *reinterpret_cast<const h8*>(                               \
          wh + (((size_t)(J) * II + i) * 16 + lm) * 8);                         \
      ACC = __builtin_amdgcn_mfma_f32_16x16x32_f16(a, bv, ACC, 0, 0, 0);        \
    }
    MM(0, acc0) MM(1, acc1) MM(2, acc2) MM(3, acc3) MM(4, acc4_)
    MM(5, acc5) MM(6, acc6) MM(7, acc7) MM(8, acc8) MM(9, acc9)
#undef MM
  }
  float* base = part + (size_t)chunk * SJE;
#define ST(J, ACC)                                                        \
  {                                                                       \
    _Pragma("unroll")                                                     \
    for (int r = 0; r < 4; ++r)                                           \
      base[((size_t)(mb + lg * 4 + r) * JJ + (J)) * 16 + lm] = ACC[r];    \
  }
  ST(0, acc0) ST(1, acc1) ST(2, acc2) ST(3, acc3) ST(4, acc4_)
  ST(5, acc5) ST(6, acc6) ST(7, acc7) ST(8, acc8) ST(9, acc9)
#undef ST
}

// -------- PASS1/2: swapped-operand MFMA routing, maskless 4x-replicated --------
// Round-20 structure. New: uh packed via v_cvt_pkrtz (2 ops/j) and accumulated
// in h4 with v_pk_fma_f16 (2 ops/j, 8 f16 terms per wave-chunk -> f32 combine).
template<int PASS>
__global__ __launch_bounds__(128)
void routing_mfma(const _Float16* __restrict__ xh, const _Float16* __restrict__ wh,
                  const float* __restrict__ o_eff, float* __restrict__ part,
                  float* __restrict__ out) {
  __shared__ __align__(16) float ols[16 * 164];   // o/4 during loop; acc-combine after
  __shared__ _Float16 c_tile[(PASS == 2) ? (16 * JJ * CPAD) : 4];

  const int t = threadIdx.x;
  const int w = t >> 6;                // wave 0/1
  const int lane = t & 63;
  const int lm = lane & 15;            // b-sub (MFMA col)
  const int eg = lane >> 4;            // e-group (MFMA row quad)
  const int ic = blockIdx.x;           // i-chunk (XCD = ic % 8)
  const int b0 = blockIdx.y * 16;
  const int b = b0 + lm;
  const int i0 = ic * ICH;

  // stage o/4 -> LDS: 640 float4 slots, row stride 164 floats
  for (int s = t; s < 640; s += 128) {
    const int bb = s / 40, rem = s - bb * 40;
    const float4 v = *reinterpret_cast<const float4*>(
        o_eff + (size_t)(b0 + bb) * 160 + rem * 4);
    float4 sv;
    sv.x = 0.25f * v.x; sv.y = 0.25f * v.y; sv.z = 0.25f * v.z; sv.w = 0.25f * v.w;
    *reinterpret_cast<float4*>(&ols[bb * 164 + rem * 4]) = sv;
  }
  __syncthreads();

  h4 acc_h[JJ];                        // f16 chunk accumulator (8 terms/wave)
#pragma unroll
  for (int j = 0; j < JJ; ++j) acc_h[j] = h4{0, 0, 0, 0};

  const f32x4 z4 = {0.f, 0.f, 0.f, 0.f};
  const _Float16* wp = wh + lm * 8;            // per-lane W base
  const _Float16* xp = xh + (size_t)b * II * 8;
  const int ibeg = i0 + w * 8;

  h8 wf[JJ];
  h8 xf;
  // prologue: load i = ibeg (all lanes, unmasked)
#pragma unroll
  for (int j = 0; j < JJ; ++j)
    wf[j] = *reinterpret_cast<const h8*>(wp + ((size_t)j * II + ibeg) * 128);
  xf = *reinterpret_cast<const h8*>(xp + (size_t)ibeg * 8);

#pragma unroll 1
  for (int ii = 0; ii < 8; ++ii) {
    const int il = w * 8 + ii;
    const int inx = ibeg + ((ii < 7) ? ii + 1 : ii);   // clamp: redundant last load

    // MFMA + logit partial + pk-pack (uh transient per j)
    float lg[JJ];
    h4 up[JJ];
#pragma unroll
    for (int j = 0; j < JJ; ++j) {
      const f32x4 uhj =
          __builtin_amdgcn_mfma_f32_16x16x32_f16(wf[j], xf, z4, 0, 0, 0);
      const float4 o4 = *reinterpret_cast<const float4*>(
          &ols[lm * 164 + j * 16 + eg * 4]);           // o/4 -> logits exact f32
      float v = o4.x * uhj[0];
      v = fmaf(o4.y, uhj[1], v);
      v = fmaf(o4.z, uhj[2], v);
      v = fmaf(o4.w, uhj[3], v);
      lg[j] = v;
      const h2 lo = pkrtz(uhj[0], uhj[1]);
      const h2 hi = pkrtz(uhj[2], uhj[3]);
      h4 u; u.x = lo.x; u.y = lo.y; u.z = hi.x; u.w = hi.y;
      up[j] = u;
    }

    // batched reloads for i+1 (no masks; WAR-free: all MFMAs above consumed wf)
#pragma unroll
    for (int j = 0; j < JJ; ++j)
      wf[j] = *reinterpret_cast<const h8*>(wp + ((size_t)j * II + inx) * 128);
    xf = *reinterpret_cast<const h8*>(xp + (size_t)inx * 8);

    // softmax (covers the reloads' latency)
    float p[JJ];
#pragma unroll
    for (int j = 0; j < JJ; ++j) {
      float v = lg[j];
      v += xor16swz(v);             // eg pairs
      v += __shfl_xor(v, 32);       // halves -> full e-sum
      p[j] = __expf(v);             // no max-sub: logits bounded, fp32 safe
    }
    const float d01 = p[0] + p[1], d23 = p[2] + p[3];
    const float d45 = p[4] + p[5], d67 = p[6] + p[7];
    const float d89 = p[8] + p[9];
    const float D = (d01 + d23) + (d45 + d67) + d89;
    const float rD = __builtin_amdgcn_rcpf(D);
#pragma unroll
    for (int j = 0; j < JJ; ++j) {
      const float c = p[j] * rD;
      const h2 ch = pkrtz(c, c);
      h4 cc; cc.x = ch.x; cc.y = ch.y; cc.z = ch.x; cc.w = ch.y;
      acc_h[j] = __builtin_elementwise_fma(cc, up[j], acc_h[j]);  // v_pk_fma_f16
      if (PASS == 2) {
        const int owner = (j >= 9) ? 3 : (j / 3);
        if (eg == owner)
          c_tile[(lm * JJ + j) * CPAD + il] = (_Float16)c;
      }
    }
  }

  // promote h4 acc -> f32 (once per wave-chunk)
  f32x4 acc[JJ];
#pragma unroll
  for (int j = 0; j < JJ; ++j) {
    f32x4 a;
    a[0] = (float)acc_h[j].x; a[1] = (float)acc_h[j].y;
    a[2] = (float)acc_h[j].z; a[3] = (float)acc_h[j].w;
    acc[j] = a;
  }

  // combine the two waves' acc (reuse ols as the combine buffer) and store part
  __syncthreads();                  // o reads done; c_tile writes done
  if (w == 0) {
#pragma unroll
    for (int j = 0; j < JJ; ++j)
      *reinterpret_cast<f32x4*>(&ols[lm * 164 + j * 16 + eg * 4]) = acc[j];
  }
  __syncthreads();
  if (w == 1) {
#pragma unroll
    for (int j = 0; j < JJ; ++j) {
      f32x4 v = *reinterpret_cast<const f32x4*>(&ols[lm * 164 + j * 16 + eg * 4]);
      v += acc[j];
      *reinterpret_cast<f32x4*>(
          part + (size_t)ic * SJE + ((size_t)b * JJ + j) * 16 + eg * 4) = v;
    }
  }

  if (PASS == 2) {
    // coalesced c out: 160 rows x 16 i-floats
    for (int s = t; s < 16 * JJ * (ICH / 4); s += 128) {
      const int row = s >> 2, q = s & 3;
      const int bb = row / JJ, jj = row - bb * JJ;
      const h4 cv = *reinterpret_cast<const h4*>(&c_tile[row * CPAD + q * 4]);
      float4 ov;
      ov.x = (float)cv.x; ov.y = (float)cv.y; ov.z = (float)cv.z; ov.w = (float)cv.w;
      *reinterpret_cast<float4*>(
          out + ((size_t)(b0 + bb) * JJ + jj) * 2064 + 16 + i0 + q * 4) = ov;
    }
  }
}

// fused: reduce over 128 i-chunk partials + squash + output/o_eff update
// pass0: part holds true sums (c=0.1 deferred). pass1/2: part holds 4x sums
// (maskless MFMA replication) -> scale 0.25.
__global__ __launch_bounds__(256)
void finish_pass(const float* __restrict__ part, float* __restrict__ o_eff,
                 float* __restrict__ out, int pass) {
  const int idx = blockIdx.x * 256 + threadIdx.x;
  float a = 0.f;
#pragma unroll 8
  for (int k = 0; k < ICHUNKS; ++k) a += part[(size_t)k * SJE + idx];
  a *= (pass == 0) ? 0.1f : 0.25f;
  const float s2 = rsum16(a * a);
  const float scale = s2 / ((1.f + s2) * sqrtf(s2 + 1e-7f));
  const float v = scale * a;
  if (pass == 0) o_eff[idx] = v;
  else if (pass == 1) o_eff[idx] += v;
  else out[(size_t)(idx >> 4) * 2064 + (idx & 15)] = v;
}

// -------- fp32 atomic fallback (round-13-proven), used only if ws too small --------
#define BBLK 32
#define NBW 8
template<int PASS>
__global__ __launch_bounds__(256, 1)
void routing_pass_atomic(const float* __restrict__ x, const float* __restrict__ W,
                         const float* __restrict__ o_eff, float* __restrict__ sdst,
                         float* __restrict__ out) {
  __shared__ __align__(16) float x_lds[BBLK * ICH * 8];
  __shared__ _Float16 c_tile[(PASS == 2) ? (BBLK * JJ * 18) : 4];

  const int t = threadIdx.x;
  const int wid = t >> 6;
  const int lane = t & 63;
  const int eg = lane >> 4;
  const int j = lane & 15;
  const int jv = (j < JJ);
  const int jr = jv ? j : 0;
  const int ic = blockIdx.x;
  const int b0 = blockIdx.y * BBLK;
  const int bw = __builtin_amdgcn_readfirstlane(b0 + wid * NBW);
  const int i0 = ic * ICH;
  const float* wbase = W + ((size_t)jr * II + i0) * 128 + eg * 32;

  float4 o4[NBW];
  if (PASS > 0) {
#pragma unroll
    for (int nb = 0; nb < NBW; ++nb)
      o4[nb] = *reinterpret_cast<const float4*>(
          o_eff + ((size_t)(bw + nb) * JJ + jr) * 16 + eg * 4);
  }
  float4 acc4[NBW];
#pragma unroll
  for (int nb = 0; nb < NBW; ++nb) acc4[nb] = make_float4(0.f, 0.f, 0.f, 0.f);

#pragma unroll
  for (int k = 0; k < 4; ++k) {
    const int s = k * 256 + t;
    const int bl = s >> 5, rem = s & 31, il = rem >> 1, h = rem & 1;
    gload16(x + ((size_t)(b0 + bl) * II + i0 + il) * 8 + h * 4,
            &x_lds[(k * 256 + wid * 64) * 4]);
  }
  __syncthreads();

#pragma unroll 1
  for (int il = 0; il < ICH; ++il) {
    const float* wp = wbase + il * 128;
    float4 wv[8];
#pragma unroll
    for (int r = 0; r < 8; ++r)
      wv[r] = *reinterpret_cast<const float4*>(wp + r * 4);
#pragma unroll
    for (int nb = 0; nb < NBW; ++nb) {
      const float* xp = &x_lds[((wid * NBW + nb) * ICH + il) * 8];
      const float4 xa = *reinterpret_cast<const float4*>(xp);
      const float4 xb = *reinterpret_cast<const float4*>(xp + 4);
#define DOT8F(q, dst)                                  \
      float dst = wv[2*(q)].x * xa.x;                  \
      dst = fmaf(wv[2*(q)].y, xa.y, dst);              \
      dst = fmaf(wv[2*(q)].z, xa.z, dst);              \
      dst = fmaf(wv[2*(q)].w, xa.w, dst);              \
      dst = fmaf(wv[2*(q)+1].x, xb.x, dst);            \
      dst = fmaf(wv[2*(q)+1].y, xb.y, dst);            \
      dst = fmaf(wv[2*(q)+1].z, xb.z, dst);            \
      dst = fmaf(wv[2*(q)+1].w, xb.w, dst);
      DOT8F(0, u0) DOT8F(1, u1) DOT8F(2, u2) DOT8F(3, u3)
#undef DOT8F
      float c;
      if (PASS == 0) {
        c = 0.1f;
      } else {
        float lp = o4[nb].x * u0;
        lp = fmaf(o4[nb].y, u1, lp);
        lp = fmaf(o4[nb].z, u2, lp);
        lp = fmaf(o4[nb].w, u3, lp);
        lp += xor16swz(lp);
        lp += __shfl_xor(lp, 32);
        const float pp = jv ? __expf(lp) : 0.f;
        const float su = rsum16(pp);
        c = pp * __builtin_amdgcn_rcpf(su);
      }
      acc4[nb].x = fmaf(c, u0, acc4[nb].x);
      acc4[nb].y = fmaf(c, u1, acc4[nb].y);
      acc4[nb].z = fmaf(c, u2, acc4[nb].z);
      acc4[nb].w = fmaf(c, u3, acc4[nb].w);
      if (PASS == 2) {
        if (eg == 0 && jv)
          c_tile[((wid * NBW + nb) * JJ + j) * 18 + il] = (_Float16)c;
      }
    }
  }

  if (PASS == 2) {
    __syncthreads();
    for (int s = t; s < BBLK * JJ * ICH; s += 256) {
      const int row = s >> 4, col = s & 15;
      const int bb = row / 10, jj = row - bb * 10;
      out[((size_t)(b0 + bb) * JJ + jj) * 2064 + 16 + i0 + col] =
          (float)c_tile[row * 18 + col];
    }
  }

  if (jv) {
#pragma unroll
    for (int nb = 0; nb < NBW; ++nb) {
      float* sp = sdst + ((size_t)(bw + nb) * JJ + j) * 16 + eg * 4;
      atomicAdd(&sp[0], acc4[nb].x);
      atomicAdd(&sp[1], acc4[nb].y);
      atomicAdd(&sp[2], acc4[nb].z);
      atomicAdd(&sp[3], acc4[nb].w);
    }
  }
}

__global__ __launch_bounds__(256)
void squash_update(const float* __restrict__ s, float* __restrict__ o_eff,
                   float* __restrict__ out, int pass) {
  const int idx = blockIdx.x * blockDim.x + threadIdx.x;
  if (idx >= BB * JJ) return;
  const float* sp = s + (size_t)idx * 16;
  const float pre = (pass == 0) ? 0.1f : 1.f;
  float v[16];
  float s2 = 0.f;
#pragma unroll
  for (int e = 0; e < 16; ++e) { v[e] = pre * sp[e]; s2 = fmaf(v[e], v[e], s2); }
  const float scale = s2 / ((1.f + s2) * sqrtf(s2 + 1e-7f));
  if (pass == 0) {
    float* op = o_eff + (size_t)idx * 16;
#pragma unroll
    for (int e = 0; e < 16; ++e) op[e] = scale * v[e];
  } else if (pass == 1) {
    float* op = o_eff + (size_t)idx * 16;
#pragma unroll
    for (int e = 0; e < 16; ++e) op[e] += scale * v[e];
  } else {
    float* dst = out + (size_t)idx * 2064;
#pragma unroll
    for (int e = 0; e < 16; ++e) dst[e] = scale * v[e];
  }
}

extern "C" void kernel_launch(void* const* d_in, const int* in_sizes, int n_in,
                              void* d_out, int out_size, void* d_ws, size_t ws_size,
                              hipStream_t stream) {
  const float* x = (const float*)d_in[0];   // [256,2048,8]
  const float* W = (const float*)d_in[1];   // [10,2048,16,8]
  float* out = (float*)d_out;               // [256,10,2064]
  float* ws = (float*)d_ws;

  // ws: part | oe | xh | wh
  const size_t part_f = (size_t)ICHUNKS * SJE;              // 5242880 floats
  const size_t xh_f   = (size_t)BB * II * 8 / 2;            // 2097152 float-equivalents
  const size_t wh_f   = (size_t)JJ * II * 128 / 2;          // 1310720
  const size_t need = (part_f + SJE + xh_f + wh_f) * sizeof(float); // ~34.8 MB

  if (ws_size >= need) {
    float* part = ws;
    float* oe   = ws + part_f;
    _Float16* xh = (_Float16*)(ws + part_f + SJE);
    _Float16* wh = (_Float16*)(ws + part_f + SJE + xh_f);
    prep_half<<<2048, 256, 0, stream>>>(x, W, xh, wh);
    pass0_mfma<<<dim3(32, 16), 256, 0, stream>>>(xh, wh, part);
    finish_pass<<<SJE / 256, 256, 0, stream>>>(part, oe, out, 0);
    routing_mfma<1><<<dim3(ICHUNKS, 16), 128, 0, stream>>>(xh, wh, oe, part, nullptr);
    finish_pass<<<SJE / 256, 256, 0, stream>>>(part, oe, out, 1);
    routing_mfma<2><<<dim3(ICHUNKS, 16), 128, 0, stream>>>(xh, wh, oe, part, out);
    finish_pass<<<SJE / 256, 256, 0, stream>>>(part, oe, out, 2);
  } else {
    float* s0 = ws;
    float* s1 = ws + SJE;
    float* s2 = ws + 2 * SJE;
    float* oe = ws + 3 * SJE;
    (void)hipMemsetAsync(ws, 0, (size_t)4 * SJE * sizeof(float), stream);
    routing_pass_atomic<0><<<dim3(ICHUNKS, BB / BBLK), 256, 0, stream>>>(x, W, nullptr, s0, nullptr);
    squash_update<<<10, 256, 0, stream>>>(s0, oe, out, 0);
    routing_pass_atomic<1><<<dim3(ICHUNKS, BB / BBLK), 256, 0, stream>>>(x, W, oe, s1, nullptr);
    squash_update<<<10, 256, 0, stream>>>(s1, oe, out, 1);
    routing_pass_atomic<2><<<dim3(ICHUNKS, BB / BBLK), 256, 0, stream>>>(x, W, oe, s2, out);
    squash_update<<<10, 256, 0, stream>>>(s2, oe, out, 2);
  }
}

// Round 23
// 106.227 us; speedup vs baseline: 1.2573x; 1.0093x over previous
//
#include <hip/hip_runtime.h>
#include <math.h>

#define II 2048
#define BB 256
#define JJ 10
#define ICH 16            // i's per block
#define ICHUNKS (II/ICH)  // 128
#define SJE (BB*JJ*16)    // 40960
#define CPAD 20           // c_tile row stride (halves)

typedef __attribute__((address_space(3))) unsigned lds_u32;
typedef __attribute__((address_space(1))) const unsigned glb_u32;
typedef _Float16 h2 __attribute__((ext_vector_type(2)));
typedef _Float16 h4 __attribute__((ext_vector_type(4)));
typedef _Float16 h8 __attribute__((ext_vector_type(8)));
typedef __attribute__((ext_vector_type(4))) float f32x4;
typedef int v2i __attribute__((ext_vector_type(2)));

__device__ __forceinline__ void gload16(const void* g, void* l) {
  __builtin_amdgcn_global_load_lds((glb_u32*)g, (lds_u32*)l, 16, 0, 0);
}

__device__ __forceinline__ h2 pkrtz(float a, float b) {
#if __has_builtin(__builtin_amdgcn_cvt_pkrtz)
  auto r = __builtin_amdgcn_cvt_pkrtz(a, b);   // __fp16x2 -> bit-cast to h2
  h2 o;
  __builtin_memcpy(&o, &r, sizeof(o));
  return o;
#else
  h2 r; r.x = (_Float16)a; r.y = (_Float16)b; return r;
#endif
}

// DPP row (16-lane) rotate: VALU-pipe cross-lane, no LDS traffic.
template<int N>
__device__ __forceinline__ float rrot16(float v) {
  const int i = __float_as_int(v);
  return __int_as_float(__builtin_amdgcn_update_dpp(i, i, 0x120 + N, 0xF, 0xF, false));
}
__device__ __forceinline__ float rsum16(float v) {
  v += rrot16<8>(v); v += rrot16<4>(v); v += rrot16<2>(v); v += rrot16<1>(v);
  return v;
}
__device__ __forceinline__ float xor16swz(float v) {  // lane ^ 16 (LDS-pipe fallback)
  return __int_as_float(__builtin_amdgcn_ds_swizzle(__float_as_int(v), 0x401F));
}
// own + xor-partner sums on the VALU pipe (permlane*_swap, verified r11/m255):
__device__ __forceinline__ float xsum16p(float v) {
#if __has_builtin(__builtin_amdgcn_permlane16_swap)
  v2i r = __builtin_amdgcn_permlane16_swap(__float_as_int(v), __float_as_int(v),
                                           false, false);
  return __int_as_float(r.x) + __int_as_float(r.y);
#else
  return v + xor16swz(v);
#endif
}
__device__ __forceinline__ float xsum32p(float v) {
#if __has_builtin(__builtin_amdgcn_permlane32_swap)
  v2i r = __builtin_amdgcn_permlane32_swap(__float_as_int(v), __float_as_int(v),
                                           false, false);
  return __int_as_float(r.x) + __int_as_float(r.y);
#else
  return v + __shfl_xor(v, 32);
#endif
}

// -------- prep: fp32 -> f16 copies of x and W in ws --------
#define XF4 (BB * II * 8 / 4)        // 1048576 float4 slots
#define WF4 (JJ * II * 128 / 4)      // 655360
__global__ __launch_bounds__(256)
void prep_half(const float* __restrict__ x, const float* __restrict__ W,
               _Float16* __restrict__ xh, _Float16* __restrict__ wh) {
  for (int s = blockIdx.x * 256 + threadIdx.x; s < XF4 + WF4; s += gridDim.x * 256) {
    const float4 v = (s < XF4) ? *reinterpret_cast<const float4*>(x + (size_t)s * 4)
                               : *reinterpret_cast<const float4*>(W + (size_t)(s - XF4) * 4);
    h4 o; o.x = (_Float16)v.x; o.y = (_Float16)v.y; o.z = (_Float16)v.z; o.w = (_Float16)v.w;
    _Float16* dst = (s < XF4) ? (xh + (size_t)s * 4) : (wh + (size_t)(s - XF4) * 4);
    *reinterpret_cast<h4*>(dst) = o;
  }
}

// -------- PASS0 as f16 MFMA GEMM (s0 = x.W^T over (i,d); c==0.1 deferred) --------
__global__ __launch_bounds__(256)
void pass0_mfma(const _Float16* __restrict__ xh, const _Float16* __restrict__ wh,
                float* __restrict__ part) {
  const int t = threadIdx.x, wid = t >> 6, lane = t & 63;
  const int lg = lane >> 4, lm = lane & 15;
  const int chunk = blockIdx.x * 4 + wid;      // 0..127
  const int mb = blockIdx.y * 16;
  f32x4 acc0 = {0,0,0,0}, acc1 = {0,0,0,0}, acc2 = {0,0,0,0}, acc3 = {0,0,0,0};
  f32x4 acc4_ = {0,0,0,0}, acc5 = {0,0,0,0}, acc6 = {0,0,0,0}, acc7 = {0,0,0,0};
  f32x4 acc8 = {0,0,0,0}, acc9 = {0,0,0,0};
  const int ibase = chunk * 16;
#pragma unroll
  for (int ks = 0; ks < 4; ++ks) {
    const int i = ibase + ks * 4 + lg;
    const h8 a = *reinterpret_cast<const h8*>(xh + ((size_t)(mb + lm) * II + i) * 8);
#define MM(J, ACC)                                                              \
    {                                                                           \
      const h8 bv = *reinterpret_cast<const h8*>(                               \
          wh + (((size_t)(J) * II + i) * 16 + lm) * 8);                         \
      ACC = __builtin_amdgcn_mfma_f32_16x16x32_f16(a, bv, ACC, 0, 0, 0);        \
    }
    MM(0, acc0) MM(1, acc1) MM(2, acc2) MM(3, acc3) MM(4, acc4_)
    MM(5, acc5) MM(6, acc6) MM(7, acc7) MM(8, acc8) MM(9, acc9)
#undef MM
  }
  float* base = part + (size_t)chunk * SJE;
#define ST(J, ACC)                                                        \
  {                                                                       \
    _Pragma("unroll")                                                     \
    for (int r = 0; r < 4; ++r)                                           \
      base[((size_t)(mb + lg * 4 + r) * JJ + (J)) * 16 + lm] = ACC[r];    \
  }
  ST(0, acc0) ST(1, acc1) ST(2, acc2) ST(3, acc3) ST(4, acc4_)
  ST(5, acc5) ST(6, acc6) ST(7, acc7) ST(8, acc8) ST(9, acc9)
#undef ST
}

// -------- PASS1/2: swapped-operand MFMA routing, maskless 4x-replicated --------
// Round-22 structure. New: e-reduce on the VALU pipe (permlane16/32_swap)
// instead of ds_swizzle/ds_bpermute -- removes 20 LDS-pipe latency ops per i
// from the serial softmax chain.
template<int PASS>
__global__ __launch_bounds__(128)
void routing_mfma(const _Float16* __restrict__ xh, const _Float16* __restrict__ wh,
                  const float* __restrict__ o_eff, float* __restrict__ part,
                  float* __restrict__ out) {
  __shared__ __align__(16) float ols[16 * 164];   // o/4 during loop; acc-combine after
  __shared__ _Float16 c_tile[(PASS == 2) ? (16 * JJ * CPAD) : 4];

  const int t = threadIdx.x;
  const int w = t >> 6;                // wave 0/1
  const int lane = t & 63;
  const int lm = lane & 15;            // b-sub (MFMA col)
  const int eg = lane >> 4;            // e-group (MFMA row quad)
  const int ic = blockIdx.x;           // i-chunk (XCD = ic % 8)
  const int b0 = blockIdx.y * 16;
  const int b = b0 + lm;
  const int i0 = ic * ICH;

  // stage o/4 -> LDS: 640 float4 slots, row stride 164 floats
  for (int s = t; s < 640; s += 128) {
    const int bb = s / 40, rem = s - bb * 40;
    const float4 v = *reinterpret_cast<const float4*>(
        o_eff + (size_t)(b0 + bb) * 160 + rem * 4);
    float4 sv;
    sv.x = 0.25f * v.x; sv.y = 0.25f * v.y; sv.z = 0.25f * v.z; sv.w = 0.25f * v.w;
    *reinterpret_cast<float4*>(&ols[bb * 164 + rem * 4]) = sv;
  }
  __syncthreads();

  h4 acc_h[JJ];                        // f16 chunk accumulator (8 terms/wave)
#pragma unroll
  for (int j = 0; j < JJ; ++j) acc_h[j] = h4{0, 0, 0, 0};

  const f32x4 z4 = {0.f, 0.f, 0.f, 0.f};
  const _Float16* wp = wh + lm * 8;            // per-lane W base
  const _Float16* xp = xh + (size_t)b * II * 8;
  const int ibeg = i0 + w * 8;

  h8 wf[JJ];
  h8 xf;
  // prologue: load i = ibeg (all lanes, unmasked)
#pragma unroll
  for (int j = 0; j < JJ; ++j)
    wf[j] = *reinterpret_cast<const h8*>(wp + ((size_t)j * II + ibeg) * 128);
  xf = *reinterpret_cast<const h8*>(xp + (size_t)ibeg * 8);

#pragma unroll 1
  for (int ii = 0; ii < 8; ++ii) {
    const int il = w * 8 + ii;
    const int inx = ibeg + ((ii < 7) ? ii + 1 : ii);   // clamp: redundant last load

    // MFMA + logit partial + pk-pack (uh transient per j)
    float lg[JJ];
    h4 up[JJ];
#pragma unroll
    for (int j = 0; j < JJ; ++j) {
      const f32x4 uhj =
          __builtin_amdgcn_mfma_f32_16x16x32_f16(wf[j], xf, z4, 0, 0, 0);
      const float4 o4 = *reinterpret_cast<const float4*>(
          &ols[lm * 164 + j * 16 + eg * 4]);           // o/4 -> logits exact f32
      float v = o4.x * uhj[0];
      v = fmaf(o4.y, uhj[1], v);
      v = fmaf(o4.z, uhj[2], v);
      v = fmaf(o4.w, uhj[3], v);
      lg[j] = v;
      const h2 lo = pkrtz(uhj[0], uhj[1]);
      const h2 hi = pkrtz(uhj[2], uhj[3]);
      h4 u; u.x = lo.x; u.y = lo.y; u.z = hi.x; u.w = hi.y;
      up[j] = u;
    }

    // batched reloads for i+1 (no masks; WAR-free: all MFMAs above consumed wf)
#pragma unroll
    for (int j = 0; j < JJ; ++j)
      wf[j] = *reinterpret_cast<const h8*>(wp + ((size_t)j * II + inx) * 128);
    xf = *reinterpret_cast<const h8*>(xp + (size_t)inx * 8);

    // softmax (VALU-pipe cross-lane; covers the reloads' latency)
    float p[JJ];
#pragma unroll
    for (int j = 0; j < JJ; ++j) {
      float v = lg[j];
      v = xsum16p(v);               // + lane^16 (permlane16_swap, VALU)
      v = xsum32p(v);               // + lane^32 (permlane32_swap, VALU)
      p[j] = __expf(v);             // no max-sub: logits bounded, fp32 safe
    }
    const float d01 = p[0] + p[1], d23 = p[2] + p[3];
    const float d45 = p[4] + p[5], d67 = p[6] + p[7];
    const float d89 = p[8] + p[9];
    const float D = (d01 + d23) + (d45 + d67) + d89;
    const float rD = __builtin_amdgcn_rcpf(D);
#pragma unroll
    for (int j = 0; j < JJ; ++j) {
      const float c = p[j] * rD;
      const h2 ch = pkrtz(c, c);
      h4 cc; cc.x = ch.x; cc.y = ch.y; cc.z = ch.x; cc.w = ch.y;
      acc_h[j] = __builtin_elementwise_fma(cc, up[j], acc_h[j]);  // v_pk_fma_f16
      if (PASS == 2) {
        const int owner = (j >= 9) ? 3 : (j / 3);
        if (eg == owner)
          c_tile[(lm * JJ + j) * CPAD + il] = (_Float16)c;
      }
    }
  }

  // promote h4 acc -> f32 (once per wave-chunk)
  f32x4 acc[JJ];
#pragma unroll
  for (int j = 0; j < JJ; ++j) {
    f32x4 a;
    a[0] = (float)acc_h[j].x; a[1] = (float)acc_h[j].y;
    a[2] = (float)acc_h[j].z; a[3] = (float)acc_h[j].w;
    acc[j] = a;
  }

  // combine the two waves' acc (reuse ols as the combine buffer) and store part
  __syncthreads();                  // o reads done; c_tile writes done
  if (w == 0) {
#pragma unroll
    for (int j = 0; j < JJ; ++j)
      *reinterpret_cast<f32x4*>(&ols[lm * 164 + j * 16 + eg * 4]) = acc[j];
  }
  __syncthreads();
  if (w == 1) {
#pragma unroll
    for (int j = 0; j < JJ; ++j) {
      f32x4 v = *reinterpret_cast<const f32x4*>(&ols[lm * 164 + j * 16 + eg * 4]);
      v += acc[j];
      *reinterpret_cast<f32x4*>(
          part + (size_t)ic * SJE + ((size_t)b * JJ + j) * 16 + eg * 4) = v;
    }
  }

  if (PASS == 2) {
    // coalesced c out: 160 rows x 16 i-floats
    for (int s = t; s < 16 * JJ * (ICH / 4); s += 128) {
      const int row = s >> 2, q = s & 3;
      const int bb = row / JJ, jj = row - bb * JJ;
      const h4 cv = *reinterpret_cast<const h4*>(&c_tile[row * CPAD + q * 4]);
      float4 ov;
      ov.x = (float)cv.x; ov.y = (float)cv.y; ov.z = (float)cv.z; ov.w = (float)cv.w;
      *reinterpret_cast<float4*>(
          out + ((size_t)(b0 + bb) * JJ + jj) * 2064 + 16 + i0 + q * 4) = ov;
    }
  }
}

// fused: reduce over 128 i-chunk partials + squash + output/o_eff update
// pass0: part holds true sums (c=0.1 deferred). pass1/2: part holds 4x sums
// (maskless MFMA replication) -> scale 0.25.
__global__ __launch_bounds__(256)
void finish_pass(const float* __restrict__ part, float* __restrict__ o_eff,
                 float* __restrict__ out, int pass) {
  const int idx = blockIdx.x * 256 + threadIdx.x;
  float a = 0.f;
#pragma unroll 8
  for (int k = 0; k < ICHUNKS; ++k) a += part[(size_t)k * SJE + idx];
  a *= (pass == 0) ? 0.1f : 0.25f;
  const float s2 = rsum16(a * a);
  const float scale = s2 / ((1.f + s2) * sqrtf(s2 + 1e-7f));
  const float v = scale * a;
  if (pass == 0) o_eff[idx] = v;
  else if (pass == 1) o_eff[idx] += v;
  else out[(size_t)(idx >> 4) * 2064 + (idx & 15)] = v;
}

// -------- fp32 atomic fallback (round-13-proven), used only if ws too small --------
#define BBLK 32
#define NBW 8
template<int PASS>
__global__ __launch_bounds__(256, 1)
void routing_pass_atomic(const float* __restrict__ x, const float* __restrict__ W,
                         const float* __restrict__ o_eff, float* __restrict__ sdst,
                         float* __restrict__ out) {
  __shared__ __align__(16) float x_lds[BBLK * ICH * 8];
  __shared__ _Float16 c_tile[(PASS == 2) ? (BBLK * JJ * 18) : 4];

  const int t = threadIdx.x;
  const int wid = t >> 6;
  const int lane = t & 63;
  const int eg = lane >> 4;
  const int j = lane & 15;
  const int jv = (j < JJ);
  const int jr = jv ? j : 0;
  const int ic = blockIdx.x;
  const int b0 = blockIdx.y * BBLK;
  const int bw = __builtin_amdgcn_readfirstlane(b0 + wid * NBW);
  const int i0 = ic * ICH;
  const float* wbase = W + ((size_t)jr * II + i0) * 128 + eg * 32;

  float4 o4[NBW];
  if (PASS > 0) {
#pragma unroll
    for (int nb = 0; nb < NBW; ++nb)
      o4[nb] = *reinterpret_cast<const float4*>(
          o_eff + ((size_t)(bw + nb) * JJ + jr) * 16 + eg * 4);
  }
  float4 acc4[NBW];
#pragma unroll
  for (int nb = 0; nb < NBW; ++nb) acc4[nb] = make_float4(0.f, 0.f, 0.f, 0.f);

#pragma unroll
  for (int k = 0; k < 4; ++k) {
    const int s = k * 256 + t;
    const int bl = s >> 5, rem = s & 31, il = rem >> 1, h = rem & 1;
    gload16(x + ((size_t)(b0 + bl) * II + i0 + il) * 8 + h * 4,
            &x_lds[(k * 256 + wid * 64) * 4]);
  }
  __syncthreads();

#pragma unroll 1
  for (int il = 0; il < ICH; ++il) {
    const float* wp = wbase + il * 128;
    float4 wv[8];
#pragma unroll
    for (int r = 0; r < 8; ++r)
      wv[r] = *reinterpret_cast<const float4*>(wp + r * 4);
#pragma unroll
    for (int nb = 0; nb < NBW; ++nb) {
      const float* xp = &x_lds[((wid * NBW + nb) * ICH + il) * 8];
      const float4 xa = *reinterpret_cast<const float4*>(xp);
      const float4 xb = *reinterpret_cast<const float4*>(xp + 4);
#define DOT8F(q, dst)                                  \
      float dst = wv[2*(q)].x * xa.x;                  \
      dst = fmaf(wv[2*(q)].y, xa.y, dst);              \
      dst = fmaf(wv[2*(q)].z, xa.z, dst);              \
      dst = fmaf(wv[2*(q)].w, xa.w, dst);              \
      dst = fmaf(wv[2*(q)+1].x, xb.x, dst);            \
      dst = fmaf(wv[2*(q)+1].y, xb.y, dst);            \
      dst = fmaf(wv[2*(q)+1].z, xb.z, dst);            \
      dst = fmaf(wv[2*(q)+1].w, xb.w, dst);
      DOT8F(0, u0) DOT8F(1, u1) DOT8F(2, u2) DOT8F(3, u3)
#undef DOT8F
      float c;
      if (PASS == 0) {
        c = 0.1f;
      } else {
        float lp = o4[nb].x * u0;
        lp = fmaf(o4[nb].y, u1, lp);
        lp = fmaf(o4[nb].z, u2, lp);
        lp = fmaf(o4[nb].w, u3, lp);
        lp += xor16swz(lp);
        lp += __shfl_xor(lp, 32);
        const float pp = jv ? __expf(lp) : 0.f;
        const float su = rsum16(pp);
        c = pp * __builtin_amdgcn_rcpf(su);
      }
      acc4[nb].x = fmaf(c, u0, acc4[nb].x);
      acc4[nb].y = fmaf(c, u1, acc4[nb].y);
      acc4[nb].z = fmaf(c, u2, acc4[nb].z);
      acc4[nb].w = fmaf(c, u3, acc4[nb].w);
      if (PASS == 2) {
        if (eg == 0 && jv)
          c_tile[((wid * NBW + nb) * JJ + j) * 18 + il] = (_Float16)c;
      }
    }
  }

  if (PASS == 2) {
    __syncthreads();
    for (int s = t; s < BBLK * JJ * ICH; s += 256) {
      const int row = s >> 4, col = s & 15;
      const int bb = row / 10, jj = row - bb * 10;
      out[((size_t)(b0 + bb) * JJ + jj) * 2064 + 16 + i0 + col] =
          (float)c_tile[row * 18 + col];
    }
  }

  if (jv) {
#pragma unroll
    for (int nb = 0; nb < NBW; ++nb) {
      float* sp = sdst + ((size_t)(bw + nb) * JJ + j) * 16 + eg * 4;
      atomicAdd(&sp[0], acc4[nb].x);
      atomicAdd(&sp[1], acc4[nb].y);
      atomicAdd(&sp[2], acc4[nb].z);
      atomicAdd(&sp[3], acc4[nb].w);
    }
  }
}

__global__ __launch_bounds__(256)
void squash_update(const float* __restrict__ s, float* __restrict__ o_eff,
                   float* __restrict__ out, int pass) {
  const int idx = blockIdx.x * blockDim.x + threadIdx.x;
  if (idx >= BB * JJ) return;
  const float* sp = s + (size_t)idx * 16;
  const float pre = (pass == 0) ? 0.1f : 1.f;
  float v[16];
  float s2 = 0.f;
#pragma unroll
  for (int e = 0; e < 16; ++e) { v[e] = pre * sp[e]; s2 = fmaf(v[e], v[e], s2); }
  const float scale = s2 / ((1.f + s2) * sqrtf(s2 + 1e-7f));
  if (pass == 0) {
    float* op = o_eff + (size_t)idx * 16;
#pragma unroll
    for (int e = 0; e < 16; ++e) op[e] = scale * v[e];
  } else if (pass == 1) {
    float* op = o_eff + (size_t)idx * 16;
#pragma unroll
    for (int e = 0; e < 16; ++e) op[e] += scale * v[e];
  } else {
    float* dst = out + (size_t)idx * 2064;
#pragma unroll
    for (int e = 0; e < 16; ++e) dst[e] = scale * v[e];
  }
}

extern "C" void kernel_launch(void* const* d_in, const int* in_sizes, int n_in,
                              void* d_out, int out_size, void* d_ws, size_t ws_size,
                              hipStream_t stream) {
  const float* x = (const float*)d_in[0];   // [256,2048,8]
  const float* W = (const float*)d_in[1];   // [10,2048,16,8]
  float* out = (float*)d_out;               // [256,10,2064]
  float* ws = (float*)d_ws;

  // ws: part | oe | xh | wh
  const size_t part_f = (size_t)ICHUNKS * SJE;              // 5242880 floats
  const size_t xh_f   = (size_t)BB * II * 8 / 2;            // 2097152 float-equivalents
  const size_t wh_f   = (size_t)JJ * II * 128 / 2;          // 1310720
  const size_t need = (part_f + SJE + xh_f + wh_f) * sizeof(float); // ~34.8 MB

  if (ws_size >= need) {
    float* part = ws;
    float* oe   = ws + part_f;
    _Float16* xh = (_Float16*)(ws + part_f + SJE);
    _Float16* wh = (_Float16*)(ws + part_f + SJE + xh_f);
    prep_half<<<2048, 256, 0, stream>>>(x, W, xh, wh);
    pass0_mfma<<<dim3(32, 16), 256, 0, stream>>>(xh, wh, part);
    finish_pass<<<SJE / 256, 256, 0, stream>>>(part, oe, out, 0);
    routing_mfma<1><<<dim3(ICHUNKS, 16), 128, 0, stream>>>(xh, wh, oe, part, nullptr);
    finish_pass<<<SJE / 256, 256, 0, stream>>>(part, oe, out, 1);
    routing_mfma<2><<<dim3(ICHUNKS, 16), 128, 0, stream>>>(xh, wh, oe, part, out);
    finish_pass<<<SJE / 256, 256, 0, stream>>>(part, oe, out, 2);
  } else {
    float* s0 = ws;
    float* s1 = ws + SJE;
    float* s2 = ws + 2 * SJE;
    float* oe = ws + 3 * SJE;
    (void)hipMemsetAsync(ws, 0, (size_t)4 * SJE * sizeof(float), stream);
    routing_pass_atomic<0><<<dim3(ICHUNKS, BB / BBLK), 256, 0, stream>>>(x, W, nullptr, s0, nullptr);
    squash_update<<<10, 256, 0, stream>>>(s0, oe, out, 0);
    routing_pass_atomic<1><<<dim3(ICHUNKS, BB / BBLK), 256, 0, stream>>>(x, W, oe, s1, nullptr);
    squash_update<<<10, 256, 0, stream>>>(s1, oe, out, 1);
    routing_pass_atomic<2><<<dim3(ICHUNKS, BB / BBLK), 256, 0, stream>>>(x, W, oe, s2, out);
    squash_update<<<10, 256, 0, stream>>>(s2, oe, out, 2);
  }
}